// Round 1
// baseline (434.250 us; speedup 1.0000x reference)
//
#include <hip/hip_runtime.h>
#include <math.h>

#define NH 4        // heads
#define DD 64       // out features per head
#define NF 256      // NH*DD
#define KF 128      // in features
#define NN 4096     // nodes
#define NB 2        // batch
#define NG 8        // NB*NH groups

// ---------------- Kernel 1: H = X @ W  (fp32), fused s/d epilogue ----------------
// grid (128, 4): 64-row tile x one head (64 cols). B read direct from global (L1-resident).
__global__ __launch_bounds__(256) void k_gemm(const float* __restrict__ X,
                                              const float* __restrict__ W,
                                              const float* __restrict__ a_src,
                                              const float* __restrict__ a_dst,
                                              float* __restrict__ Hout,
                                              float* __restrict__ s_arr,
                                              float* __restrict__ d_arr) {
  __shared__ float As[64][132];            // padded: A-reads are 2-way (free) conflicts
  const int bm = blockIdx.x;               // 0..127
  const int bn = blockIdx.y;               // 0..3 (head)
  const int tid = threadIdx.x;

  for (int i = tid; i < 64 * 32; i += 256) {
    int r = i >> 5, c4 = i & 31;
    float4 v = *(const float4*)(X + ((size_t)(bm * 64 + r)) * KF + c4 * 4);
    *(float4*)&As[r][c4 * 4] = v;
  }
  __syncthreads();

  const int ty = tid >> 4, tx = tid & 15;
  const int col0 = bn * 64 + tx * 4;
  const float* Wp = W + col0;              // stride NF
  float acc[4][4] = {{0.f}};

  #pragma unroll 2
  for (int k4 = 0; k4 < 32; ++k4) {
    float4 a[4];
    #pragma unroll
    for (int i = 0; i < 4; ++i) a[i] = *(const float4*)&As[ty * 4 + i][k4 * 4];
    #pragma unroll
    for (int jk = 0; jk < 4; ++jk) {
      float4 b = *(const float4*)(Wp + (size_t)(k4 * 4 + jk) * NF);
      #pragma unroll
      for (int i = 0; i < 4; ++i) {
        float av = ((const float*)&a[i])[jk];
        acc[i][0] += av * b.x;
        acc[i][1] += av * b.y;
        acc[i][2] += av * b.z;
        acc[i][3] += av * b.w;
      }
    }
  }

  const float4 asv = *(const float4*)(a_src + bn * 64 + tx * 4);
  const float4 adv = *(const float4*)(a_dst + bn * 64 + tx * 4);
  const int grow0 = bm * 64 + ty * 4;
  #pragma unroll
  for (int i = 0; i < 4; ++i) {
    int grow = grow0 + i;
    float4 hv = {acc[i][0], acc[i][1], acc[i][2], acc[i][3]};
    *(float4*)(Hout + (size_t)grow * NF + col0) = hv;
    float ps = acc[i][0] * asv.x + acc[i][1] * asv.y + acc[i][2] * asv.z + acc[i][3] * asv.w;
    float pd = acc[i][0] * adv.x + acc[i][1] * adv.y + acc[i][2] * adv.z + acc[i][3] * adv.w;
    #pragma unroll
    for (int off = 1; off < 16; off <<= 1) {
      ps += __shfl_xor(ps, off);
      pd += __shfl_xor(pd, off);
    }
    if (tx == 0) {
      int b = grow >> 12, n = grow & (NN - 1);
      int g = b * NH + bn;
      s_arr[g * NN + n] = ps;
      d_arr[g * NN + n] = pd;
    }
  }
}

// ---------------- Kernel 2: per-(b,h) bitonic sort of d (key) + index ----------------
__global__ __launch_bounds__(1024) void k_sort(const float* __restrict__ d_arr,
                                               float* __restrict__ dsort,
                                               int* __restrict__ perm) {
  __shared__ float key[NN];
  __shared__ int idx[NN];
  const int g = blockIdx.x;
  for (int i = threadIdx.x; i < NN; i += 1024) { key[i] = d_arr[g * NN + i]; idx[i] = i; }
  __syncthreads();
  for (int k = 2; k <= NN; k <<= 1) {
    for (int j = k >> 1; j > 0; j >>= 1) {
      for (int i = threadIdx.x; i < NN; i += 1024) {
        int ixj = i ^ j;
        if (ixj > i) {
          float ki = key[i], kj = key[ixj];
          bool swap_needed = ((i & k) == 0) ? (ki > kj) : (ki < kj);
          if (swap_needed) {
            key[i] = kj; key[ixj] = ki;
            int t = idx[i]; idx[i] = idx[ixj]; idx[ixj] = t;
          }
        }
      }
      __syncthreads();
    }
  }
  for (int i = threadIdx.x; i < NN; i += 1024) {
    dsort[g * NN + i] = key[i];
    perm[g * NN + i] = idx[i];
  }
}

// ---------------- Kernel 3: prefix (0.2-branch) and suffix (1.0-branch) scans ----------------
// one block of 512 threads per group g; 8 waves = 8 chunks of 512; lane = channel c (64)
__global__ __launch_bounds__(512) void k_scan(const float* __restrict__ Hmat,
                                              const float* __restrict__ dsort,
                                              const int* __restrict__ perm,
                                              float* __restrict__ Ph, float* __restrict__ Sh,
                                              float* __restrict__ Pexp, float* __restrict__ Sexp) {
  __shared__ float pch[8][64], sch[8][64];
  __shared__ float pwch[8], swch[8];
  const int g = blockIdx.x;
  const int b = g >> 2, h = g & 3;
  const int c = threadIdx.x & 63, q = threadIdx.x >> 6;
  const float dmax = dsort[g * NN + (NN - 1)];
  const int k0 = q * 512, k1 = k0 + 512;

  float pa = 0.f, sa = 0.f, pw = 0.f, sw = 0.f;
  for (int k = k0; k < k1; ++k) {
    int j = perm[g * NN + k];
    float hv = Hmat[((size_t)(b * NN + j)) * NF + h * 64 + c];
    float dk = dsort[g * NN + k];
    float wp = __expf(0.2f * (dk - dmax));
    float ws = __expf(dk - dmax);
    pa += wp * hv; sa += ws * hv; pw += wp; sw += ws;
  }
  pch[q][c] = pa; sch[q][c] = sa;
  if (c == 0) { pwch[q] = pw; swch[q] = sw; }
  __syncthreads();

  float poff = 0.f, soff = 0.f, pwoff = 0.f, swoff = 0.f;
  for (int t = 0; t < q; ++t) { poff += pch[t][c]; pwoff += pwch[t]; }
  for (int t = q + 1; t < 8; ++t) { soff += sch[t][c]; swoff += swch[t]; }

  float rp = poff, rw = pwoff;
  for (int k = k0; k < k1; ++k) {
    int j = perm[g * NN + k];
    float hv = Hmat[((size_t)(b * NN + j)) * NF + h * 64 + c];
    float dk = dsort[g * NN + k];
    float wp = __expf(0.2f * (dk - dmax));
    rp += wp * hv; rw += wp;
    Ph[((size_t)g * NN + k) * 64 + c] = rp;
    if (c == 0) Pexp[g * NN + k] = rw;
  }
  float rs = soff, rsw = swoff;
  for (int k = k1 - 1; k >= k0; --k) {
    int j = perm[g * NN + k];
    float hv = Hmat[((size_t)(b * NN + j)) * NF + h * 64 + c];
    float dk = dsort[g * NN + k];
    float ws = __expf(dk - dmax);
    rs += ws * hv; rsw += ws;
    Sh[((size_t)g * NN + k) * 64 + c] = rs;
    if (c == 0) Sexp[g * NN + k] = rsw;
  }
}

// ---------------- Kernel 4: per-row combine + bias + ELU ----------------
// one wave per (g, i): 64-ary rank search (2 ballots), 2x 256B gathers, write 256B
__global__ __launch_bounds__(256) void k_out(const float* __restrict__ s_arr,
                                             const float* __restrict__ dsort,
                                             const float* __restrict__ Ph, const float* __restrict__ Sh,
                                             const float* __restrict__ Pexp, const float* __restrict__ Sexp,
                                             const float* __restrict__ bias,
                                             float* __restrict__ out) {
  const int lane = threadIdx.x & 63;
  const int task = blockIdx.x * 4 + (threadIdx.x >> 6);  // 0..32767
  const int g = task >> 12;                              // 0..7
  const int i = task & (NN - 1);
  const int b = g >> 2, h = g & 3;

  const float si = s_arr[g * NN + i];
  const float t = -si;
  const float* ds = dsort + (size_t)g * NN;
  const float dmax = ds[NN - 1];

  // 64-ary search: rank m = #{ d_j <= t }
  float probe1 = ds[lane * 64 + 63];
  unsigned long long m1 = __ballot(probe1 <= t);
  int blk = __popcll(m1);
  int m;
  if (blk == 64) {
    m = NN;
  } else {
    float probe2 = ds[blk * 64 + lane];
    unsigned long long m2 = __ballot(probe2 <= t);
    m = blk * 64 + __popcll(m2);
  }

  const float sdm = si + dmax;
  const float mx = sdm > 0.f ? sdm : 0.2f * sdm;   // true row max of LeakyReLU scores
  const float alpha = __expf(sdm - mx);
  const float beta = __expf(0.2f * sdm - mx);

  float numA = 0.f, denA = 0.f, numB = 0.f, denB = 0.f;
  if (m < NN) {
    numA = Sh[((size_t)g * NN + m) * 64 + lane];
    denA = Sexp[g * NN + m];
  }
  if (m > 0) {
    numB = Ph[((size_t)g * NN + m - 1) * 64 + lane];
    denB = Pexp[g * NN + m - 1];
  }
  const float den = alpha * denA + beta * denB;
  float val = (alpha * numA + beta * numB) / den + bias[h * 64 + lane];
  float o = val > 0.f ? val : expm1f(val);
  out[((size_t)(b * NN + i)) * NF + h * 64 + lane] = o;
}

extern "C" void kernel_launch(void* const* d_in, const int* in_sizes, int n_in,
                              void* d_out, int out_size, void* d_ws, size_t ws_size,
                              hipStream_t stream) {
  const float* X = (const float*)d_in[0];       // [2,4096,128]
  const float* W = (const float*)d_in[1];       // [128,256]
  const float* a_src = (const float*)d_in[2];   // [4,64,1]
  const float* a_dst = (const float*)d_in[3];   // [4,64,1]
  const float* bias = (const float*)d_in[4];    // [256]
  float* out = (float*)d_out;                   // [2,4096,256]

  // h lives in d_out until k_out overwrites it (k_out doesn't read h)
  float* Hmat = (float*)d_out;

  float* ws = (float*)d_ws;
  float* s_arr = ws;                    // 8*4096
  float* d_arr = s_arr + NG * NN;       // 8*4096
  float* dsort = d_arr + NG * NN;       // 8*4096
  int* perm = (int*)(dsort + NG * NN);  // 8*4096
  float* Pexp = (float*)(perm + NG * NN);
  float* Sexp = Pexp + NG * NN;
  float* Ph = Sexp + NG * NN;           // 8*4096*64
  float* Sh = Ph + (size_t)NG * NN * 64;

  k_gemm<<<dim3(128, 4), 256, 0, stream>>>(X, W, a_src, a_dst, Hmat, s_arr, d_arr);
  k_sort<<<NG, 1024, 0, stream>>>(d_arr, dsort, perm);
  k_scan<<<NG, 512, 0, stream>>>(Hmat, dsort, perm, Ph, Sh, Pexp, Sexp);
  k_out<<<32768 / 4, 256, 0, stream>>>(s_arr, dsort, Ph, Sh, Pexp, Sexp, bias, out);
}

// Round 2
// 111.316 us; speedup vs baseline: 3.9010x; 3.9010x over previous
//
#include <hip/hip_runtime.h>
#include <math.h>

#define NH 4        // heads
#define DD 64       // out features per head
#define NF 256      // NH*DD
#define KF 128      // in features
#define NN 4096     // nodes
#define NB 2        // batch
#define NG 8        // NB*NH groups
#define CH 32       // scan chunk length
#define NCH 128     // NN / CH

// ---------------- Kernel 1: H = X @ W  (fp32), fused s/d epilogue ----------------
__global__ __launch_bounds__(256) void k_gemm(const float* __restrict__ X,
                                              const float* __restrict__ W,
                                              const float* __restrict__ a_src,
                                              const float* __restrict__ a_dst,
                                              float* __restrict__ Hout,
                                              float* __restrict__ s_arr,
                                              float* __restrict__ d_arr) {
  __shared__ float As[64][132];
  const int bm = blockIdx.x;               // 0..127
  const int bn = blockIdx.y;               // 0..3 (head)
  const int tid = threadIdx.x;

  for (int i = tid; i < 64 * 32; i += 256) {
    int r = i >> 5, c4 = i & 31;
    float4 v = *(const float4*)(X + ((size_t)(bm * 64 + r)) * KF + c4 * 4);
    *(float4*)&As[r][c4 * 4] = v;
  }
  __syncthreads();

  const int ty = tid >> 4, tx = tid & 15;
  const int col0 = bn * 64 + tx * 4;
  const float* Wp = W + col0;              // stride NF
  float acc[4][4] = {{0.f}};

  #pragma unroll 2
  for (int k4 = 0; k4 < 32; ++k4) {
    float4 a[4];
    #pragma unroll
    for (int i = 0; i < 4; ++i) a[i] = *(const float4*)&As[ty * 4 + i][k4 * 4];
    #pragma unroll
    for (int jk = 0; jk < 4; ++jk) {
      float4 b = *(const float4*)(Wp + (size_t)(k4 * 4 + jk) * NF);
      #pragma unroll
      for (int i = 0; i < 4; ++i) {
        float av = ((const float*)&a[i])[jk];
        acc[i][0] += av * b.x;
        acc[i][1] += av * b.y;
        acc[i][2] += av * b.z;
        acc[i][3] += av * b.w;
      }
    }
  }

  const float4 asv = *(const float4*)(a_src + bn * 64 + tx * 4);
  const float4 adv = *(const float4*)(a_dst + bn * 64 + tx * 4);
  const int grow0 = bm * 64 + ty * 4;
  #pragma unroll
  for (int i = 0; i < 4; ++i) {
    int grow = grow0 + i;
    float4 hv = {acc[i][0], acc[i][1], acc[i][2], acc[i][3]};
    *(float4*)(Hout + (size_t)grow * NF + col0) = hv;
    float ps = acc[i][0] * asv.x + acc[i][1] * asv.y + acc[i][2] * asv.z + acc[i][3] * asv.w;
    float pd = acc[i][0] * adv.x + acc[i][1] * adv.y + acc[i][2] * adv.z + acc[i][3] * adv.w;
    #pragma unroll
    for (int off = 1; off < 16; off <<= 1) {
      ps += __shfl_xor(ps, off);
      pd += __shfl_xor(pd, off);
    }
    if (tx == 0) {
      int b = grow >> 12, n = grow & (NN - 1);
      int g = b * NH + bn;
      s_arr[g * NN + n] = ps;
      d_arr[g * NN + n] = pd;
    }
  }
}

// ---------------- Kernel 2: per-(b,h) bitonic sort; j<=32 stages fused in registers ----------------
__global__ __launch_bounds__(1024) void k_sort(const float* __restrict__ d_arr,
                                               float* __restrict__ dsort,
                                               int* __restrict__ perm) {
  __shared__ float key[NN];
  __shared__ int idx[NN];
  const int g = blockIdx.x;
  const int tid = threadIdx.x;
  const int lane = tid & 63;
  const int wave = tid >> 6;

  // Phase I: k = 2..64 entirely in registers (partner within 64-lane segment)
  #pragma unroll
  for (int ss = 0; ss < 4; ++ss) {
    const int seg = wave + ss * 16;
    const int i = seg * 64 + lane;
    float k0 = d_arr[g * NN + i];
    int id0 = i;
    #pragma unroll
    for (int k = 2; k <= 64; k <<= 1) {
      #pragma unroll
      for (int j = k >> 1; j >= 1; j >>= 1) {
        float pk = __shfl_xor(k0, j);
        int pid = __shfl_xor(id0, j);
        bool lower = (lane & j) == 0;
        bool asc = (i & k) == 0;
        float kl = lower ? k0 : pk;
        float kh = lower ? pk : k0;
        if ((kl > kh) == asc) { k0 = pk; id0 = pid; }
      }
    }
    key[i] = k0; idx[i] = id0;
  }
  __syncthreads();

  for (int k = 128; k <= NN; k <<= 1) {
    // LDS passes for j >= 64
    for (int j = k >> 1; j >= 64; j >>= 1) {
      #pragma unroll
      for (int t = 0; t < 2; ++t) {
        int pr = tid + t * 1024;                       // 0..2047 pair index
        int i = ((pr & ~(j - 1)) << 1) | (pr & (j - 1));
        int ixj = i | j;
        float ki = key[i], kj = key[ixj];
        bool asc = (i & k) == 0;
        if ((ki > kj) == asc) {
          key[i] = kj; key[ixj] = ki;
          int tmp = idx[i]; idx[i] = idx[ixj]; idx[ixj] = tmp;
        }
      }
      __syncthreads();
    }
    // register tail: j = 32..1
    #pragma unroll
    for (int ss = 0; ss < 4; ++ss) {
      const int seg = wave + ss * 16;
      const int i = seg * 64 + lane;
      float k0 = key[i];
      int id0 = idx[i];
      const bool asc = (i & k) == 0;
      #pragma unroll
      for (int j = 32; j >= 1; j >>= 1) {
        float pk = __shfl_xor(k0, j);
        int pid = __shfl_xor(id0, j);
        bool lower = (lane & j) == 0;
        float kl = lower ? k0 : pk;
        float kh = lower ? pk : k0;
        if ((kl > kh) == asc) { k0 = pk; id0 = pid; }
      }
      key[i] = k0; idx[i] = id0;
    }
    __syncthreads();
  }

  for (int i = tid; i < NN; i += 1024) {
    dsort[g * NN + i] = key[i];
    perm[g * NN + i] = idx[i];
  }
}

// ---------------- Kernel 3a: per-chunk partial sums ----------------
__global__ __launch_bounds__(64) void k_part(const float* __restrict__ Hmat,
                                             const float* __restrict__ dsort,
                                             const int* __restrict__ perm,
                                             float* __restrict__ chunkP, float* __restrict__ chunkS,
                                             float* __restrict__ chunkPw, float* __restrict__ chunkSw) {
  const int ch = blockIdx.x;   // 0..127
  const int g = blockIdx.y;    // 0..7
  const int b = g >> 2, h = g & 3;
  const int c = threadIdx.x;   // channel 0..63
  const float dmax = dsort[g * NN + NN - 1];
  const int k0 = ch * CH;

  float pa = 0.f, sa = 0.f, pw = 0.f, sw = 0.f;
  #pragma unroll 4
  for (int kk = 0; kk < CH; ++kk) {
    int k = k0 + kk;
    int j = perm[g * NN + k];
    float dk = dsort[g * NN + k];
    float hv = Hmat[((size_t)(b * NN + j)) * NF + h * 64 + c];
    float wp = __expf(0.2f * (dk - dmax));
    float ws = __expf(dk - dmax);
    pa += wp * hv; sa += ws * hv; pw += wp; sw += ws;
  }
  chunkP[(g * NCH + ch) * 64 + c] = pa;
  chunkS[(g * NCH + ch) * 64 + c] = sa;
  if (c == 0) { chunkPw[g * NCH + ch] = pw; chunkSw[g * NCH + ch] = sw; }
}

// ---------------- Kernel 3b: offsets (recomputed per block) + final scan write ----------------
__global__ __launch_bounds__(64) void k_fin(const float* __restrict__ Hmat,
                                            const float* __restrict__ dsort,
                                            const int* __restrict__ perm,
                                            const float* __restrict__ chunkP, const float* __restrict__ chunkS,
                                            const float* __restrict__ chunkPw, const float* __restrict__ chunkSw,
                                            float* __restrict__ Ph, float* __restrict__ Sh,
                                            float* __restrict__ Pexp, float* __restrict__ Sexp) {
  const int ch = blockIdx.x;   // 0..127
  const int g = blockIdx.y;    // 0..7
  const int b = g >> 2, h = g & 3;
  const int c = threadIdx.x;   // channel 0..63
  const float dmax = dsort[g * NN + NN - 1];
  const int k0 = ch * CH;

  // channel offsets: exclusive prefix over chunks < ch (P), suffix over chunks > ch (S)
  float poffv = 0.f, soffv = 0.f;
  for (int t = 0; t < ch; ++t)       poffv += chunkP[(g * NCH + t) * 64 + c];
  for (int t = ch + 1; t < NCH; ++t) soffv += chunkS[(g * NCH + t) * 64 + c];

  // scalar weight offsets: lane-parallel load + wave reduce
  float w1 = chunkPw[g * NCH + c];
  float w2 = chunkPw[g * NCH + 64 + c];
  float pwo = (c < ch ? w1 : 0.f) + (c + 64 < ch ? w2 : 0.f);
  float u1 = chunkSw[g * NCH + c];
  float u2 = chunkSw[g * NCH + 64 + c];
  float swo = (c > ch ? u1 : 0.f) + (c + 64 > ch ? u2 : 0.f);
  #pragma unroll
  for (int off = 1; off < 64; off <<= 1) {
    pwo += __shfl_xor(pwo, off);
    swo += __shfl_xor(swo, off);
  }

  float rp = poffv, rw = pwo;
  #pragma unroll 4
  for (int kk = 0; kk < CH; ++kk) {
    int k = k0 + kk;
    int j = perm[g * NN + k];
    float dk = dsort[g * NN + k];
    float hv = Hmat[((size_t)(b * NN + j)) * NF + h * 64 + c];
    float wp = __expf(0.2f * (dk - dmax));
    rp += wp * hv; rw += wp;
    Ph[((size_t)(g * NN + k)) * 64 + c] = rp;
    if (c == 0) Pexp[g * NN + k] = rw;
  }
  float rs = soffv, rsw = swo;
  #pragma unroll 4
  for (int kk = CH - 1; kk >= 0; --kk) {
    int k = k0 + kk;
    int j = perm[g * NN + k];
    float dk = dsort[g * NN + k];
    float hv = Hmat[((size_t)(b * NN + j)) * NF + h * 64 + c];
    float ws = __expf(dk - dmax);
    rs += ws * hv; rsw += ws;
    Sh[((size_t)(g * NN + k)) * 64 + c] = rs;
    if (c == 0) Sexp[g * NN + k] = rsw;
  }
}

// ---------------- Kernel 4: per-row combine + bias + ELU ----------------
__global__ __launch_bounds__(256) void k_out(const float* __restrict__ s_arr,
                                             const float* __restrict__ dsort,
                                             const float* __restrict__ Ph, const float* __restrict__ Sh,
                                             const float* __restrict__ Pexp, const float* __restrict__ Sexp,
                                             const float* __restrict__ bias,
                                             float* __restrict__ out) {
  const int lane = threadIdx.x & 63;
  const int task = blockIdx.x * 4 + (threadIdx.x >> 6);  // 0..32767
  const int g = task >> 12;                              // 0..7
  const int i = task & (NN - 1);
  const int b = g >> 2, h = g & 3;

  const float si = s_arr[g * NN + i];
  const float t = -si;
  const float* ds = dsort + (size_t)g * NN;
  const float dmax = ds[NN - 1];

  // 64-ary search: rank m = #{ d_j <= t }
  float probe1 = ds[lane * 64 + 63];
  unsigned long long m1 = __ballot(probe1 <= t);
  int blk = __popcll(m1);
  int m;
  if (blk == 64) {
    m = NN;
  } else {
    float probe2 = ds[blk * 64 + lane];
    unsigned long long m2 = __ballot(probe2 <= t);
    m = blk * 64 + __popcll(m2);
  }

  const float sdm = si + dmax;
  const float mx = sdm > 0.f ? sdm : 0.2f * sdm;   // true row max of LeakyReLU scores
  const float alpha = __expf(sdm - mx);
  const float beta = __expf(0.2f * sdm - mx);

  float numA = 0.f, denA = 0.f, numB = 0.f, denB = 0.f;
  if (m < NN) {
    numA = Sh[((size_t)g * NN + m) * 64 + lane];
    denA = Sexp[g * NN + m];
  }
  if (m > 0) {
    numB = Ph[((size_t)g * NN + m - 1) * 64 + lane];
    denB = Pexp[g * NN + m - 1];
  }
  const float den = alpha * denA + beta * denB;
  float val = (alpha * numA + beta * numB) / den + bias[h * 64 + lane];
  float o = val > 0.f ? val : expm1f(val);
  out[((size_t)(b * NN + i)) * NF + h * 64 + lane] = o;
}

extern "C" void kernel_launch(void* const* d_in, const int* in_sizes, int n_in,
                              void* d_out, int out_size, void* d_ws, size_t ws_size,
                              hipStream_t stream) {
  const float* X = (const float*)d_in[0];       // [2,4096,128]
  const float* W = (const float*)d_in[1];       // [128,256]
  const float* a_src = (const float*)d_in[2];   // [4,64,1]
  const float* a_dst = (const float*)d_in[3];   // [4,64,1]
  const float* bias = (const float*)d_in[4];    // [256]
  float* out = (float*)d_out;                   // [2,4096,256]

  // h lives in d_out until k_out overwrites it (k_out doesn't read h)
  float* Hmat = (float*)d_out;

  float* ws = (float*)d_ws;
  float* s_arr = ws;                    // 8*4096
  float* d_arr = s_arr + NG * NN;       // 8*4096
  float* dsort = d_arr + NG * NN;       // 8*4096
  int* perm = (int*)(dsort + NG * NN);  // 8*4096
  float* Pexp = (float*)(perm + NG * NN);
  float* Sexp = Pexp + NG * NN;
  float* chunkP = Sexp + NG * NN;       // 8*128*64
  float* chunkS = chunkP + NG * NCH * 64;
  float* chunkPw = chunkS + NG * NCH * 64;  // 8*128
  float* chunkSw = chunkPw + NG * NCH;
  float* Ph = chunkSw + NG * NCH;       // 8*4096*64
  float* Sh = Ph + (size_t)NG * NN * 64;

  k_gemm<<<dim3(128, 4), 256, 0, stream>>>(X, W, a_src, a_dst, Hmat, s_arr, d_arr);
  k_sort<<<NG, 1024, 0, stream>>>(d_arr, dsort, perm);
  k_part<<<dim3(NCH, NG), 64, 0, stream>>>(Hmat, dsort, perm, chunkP, chunkS, chunkPw, chunkSw);
  k_fin<<<dim3(NCH, NG), 64, 0, stream>>>(Hmat, dsort, perm, chunkP, chunkS, chunkPw, chunkSw,
                                          Ph, Sh, Pexp, Sexp);
  k_out<<<32768 / 4, 256, 0, stream>>>(s_arr, dsort, Ph, Sh, Pexp, Sexp, bias, out);
}

// Round 3
// 82.447 us; speedup vs baseline: 5.2670x; 1.3502x over previous
//
#include <hip/hip_runtime.h>
#include <math.h>

#define NH 4        // heads
#define DD 64       // out features per head
#define NF 256      // NH*DD
#define KF 128      // in features
#define NN 4096     // nodes
#define NB 2        // batch
#define NG 8        // NB*NH groups
#define CH 32       // scan chunk length
#define NCH 128     // NN / CH
#define SUB 8       // elements per wave within a chunk (4 waves * 8 = CH)

// ---------------- Kernel 1: H = X @ W  (fp32), fused s/d epilogue ----------------
__global__ __launch_bounds__(256) void k_gemm(const float* __restrict__ X,
                                              const float* __restrict__ W,
                                              const float* __restrict__ a_src,
                                              const float* __restrict__ a_dst,
                                              float* __restrict__ Hout,
                                              float* __restrict__ s_arr,
                                              float* __restrict__ d_arr) {
  __shared__ float As[64][132];
  const int bm = blockIdx.x;               // 0..127
  const int bn = blockIdx.y;               // 0..3 (head)
  const int tid = threadIdx.x;

  for (int i = tid; i < 64 * 32; i += 256) {
    int r = i >> 5, c4 = i & 31;
    float4 v = *(const float4*)(X + ((size_t)(bm * 64 + r)) * KF + c4 * 4);
    *(float4*)&As[r][c4 * 4] = v;
  }
  __syncthreads();

  const int ty = tid >> 4, tx = tid & 15;
  const int col0 = bn * 64 + tx * 4;
  const float* Wp = W + col0;              // stride NF
  float acc[4][4] = {{0.f}};

  #pragma unroll 2
  for (int k4 = 0; k4 < 32; ++k4) {
    float4 a[4];
    #pragma unroll
    for (int i = 0; i < 4; ++i) a[i] = *(const float4*)&As[ty * 4 + i][k4 * 4];
    #pragma unroll
    for (int jk = 0; jk < 4; ++jk) {
      float4 b = *(const float4*)(Wp + (size_t)(k4 * 4 + jk) * NF);
      #pragma unroll
      for (int i = 0; i < 4; ++i) {
        float av = ((const float*)&a[i])[jk];
        acc[i][0] += av * b.x;
        acc[i][1] += av * b.y;
        acc[i][2] += av * b.z;
        acc[i][3] += av * b.w;
      }
    }
  }

  const float4 asv = *(const float4*)(a_src + bn * 64 + tx * 4);
  const float4 adv = *(const float4*)(a_dst + bn * 64 + tx * 4);
  const int grow0 = bm * 64 + ty * 4;
  #pragma unroll
  for (int i = 0; i < 4; ++i) {
    int grow = grow0 + i;
    float4 hv = {acc[i][0], acc[i][1], acc[i][2], acc[i][3]};
    *(float4*)(Hout + (size_t)grow * NF + col0) = hv;
    float ps = acc[i][0] * asv.x + acc[i][1] * asv.y + acc[i][2] * asv.z + acc[i][3] * asv.w;
    float pd = acc[i][0] * adv.x + acc[i][1] * adv.y + acc[i][2] * adv.z + acc[i][3] * adv.w;
    #pragma unroll
    for (int off = 1; off < 16; off <<= 1) {
      ps += __shfl_xor(ps, off);
      pd += __shfl_xor(pd, off);
    }
    if (tx == 0) {
      int b = grow >> 12, n = grow & (NN - 1);
      int g = b * NH + bn;
      s_arr[g * NN + n] = ps;
      d_arr[g * NN + n] = pd;
    }
  }
}

// ---------------- Kernel 2: per-(b,h) bitonic sort; j<=32 stages fused in registers ----------------
__global__ __launch_bounds__(1024) void k_sort(const float* __restrict__ d_arr,
                                               float* __restrict__ dsort,
                                               int* __restrict__ perm) {
  __shared__ float key[NN];
  __shared__ int idx[NN];
  const int g = blockIdx.x;
  const int tid = threadIdx.x;
  const int lane = tid & 63;
  const int wave = tid >> 6;

  // Phase I: k = 2..64 entirely in registers (partner within 64-lane segment)
  #pragma unroll
  for (int ss = 0; ss < 4; ++ss) {
    const int seg = wave + ss * 16;
    const int i = seg * 64 + lane;
    float k0 = d_arr[g * NN + i];
    int id0 = i;
    #pragma unroll
    for (int k = 2; k <= 64; k <<= 1) {
      #pragma unroll
      for (int j = k >> 1; j >= 1; j >>= 1) {
        float pk = __shfl_xor(k0, j);
        int pid = __shfl_xor(id0, j);
        bool lower = (lane & j) == 0;
        bool asc = (i & k) == 0;
        float kl = lower ? k0 : pk;
        float kh = lower ? pk : k0;
        if ((kl > kh) == asc) { k0 = pk; id0 = pid; }
      }
    }
    key[i] = k0; idx[i] = id0;
  }
  __syncthreads();

  for (int k = 128; k <= NN; k <<= 1) {
    // LDS passes for j >= 64
    for (int j = k >> 1; j >= 64; j >>= 1) {
      #pragma unroll
      for (int t = 0; t < 2; ++t) {
        int pr = tid + t * 1024;                       // 0..2047 pair index
        int i = ((pr & ~(j - 1)) << 1) | (pr & (j - 1));
        int ixj = i | j;
        float ki = key[i], kj = key[ixj];
        bool asc = (i & k) == 0;
        if ((ki > kj) == asc) {
          key[i] = kj; key[ixj] = ki;
          int tmp = idx[i]; idx[i] = idx[ixj]; idx[ixj] = tmp;
        }
      }
      __syncthreads();
    }
    // register tail: j = 32..1
    #pragma unroll
    for (int ss = 0; ss < 4; ++ss) {
      const int seg = wave + ss * 16;
      const int i = seg * 64 + lane;
      float k0 = key[i];
      int id0 = idx[i];
      const bool asc = (i & k) == 0;
      #pragma unroll
      for (int j = 32; j >= 1; j >>= 1) {
        float pk = __shfl_xor(k0, j);
        int pid = __shfl_xor(id0, j);
        bool lower = (lane & j) == 0;
        float kl = lower ? k0 : pk;
        float kh = lower ? pk : k0;
        if ((kl > kh) == asc) { k0 = pk; id0 = pid; }
      }
      key[i] = k0; idx[i] = id0;
    }
    __syncthreads();
  }

  for (int i = tid; i < NN; i += 1024) {
    dsort[g * NN + i] = key[i];
    perm[g * NN + i] = idx[i];
  }
}

// ---------------- Kernel 3a: per-chunk partial sums (4 waves/block, batched loads) ----------------
__global__ __launch_bounds__(256) void k_part(const float* __restrict__ Hmat,
                                              const float* __restrict__ dsort,
                                              const int* __restrict__ perm,
                                              float* __restrict__ chunkP, float* __restrict__ chunkS,
                                              float* __restrict__ chunkPw, float* __restrict__ chunkSw) {
  __shared__ float subP[4][64], subS[4][64];
  __shared__ float subPw[4], subSw[4];
  const int ch = blockIdx.x;   // 0..127
  const int g = blockIdx.y;    // 0..7
  const int b = g >> 2, h = g & 3;
  const int c = threadIdx.x & 63;
  const int w = threadIdx.x >> 6;
  const int gNN = g * NN;
  const size_t bNN = (size_t)b * NN;
  const int h64 = h * 64;
  const float dmax = dsort[gNN + NN - 1];
  const int kw0 = ch * CH + w * SUB;

  int j8[SUB]; float d8[SUB], hv8[SUB];
  #pragma unroll
  for (int l = 0; l < SUB; ++l) j8[l] = perm[gNN + kw0 + l];
  #pragma unroll
  for (int l = 0; l < SUB; ++l) d8[l] = dsort[gNN + kw0 + l];
  #pragma unroll
  for (int l = 0; l < SUB; ++l) hv8[l] = Hmat[(bNN + j8[l]) * NF + h64 + c];

  float pa = 0.f, sa = 0.f, pw = 0.f, sw = 0.f;
  #pragma unroll
  for (int l = 0; l < SUB; ++l) {
    float wp = __expf(0.2f * (d8[l] - dmax));
    float ws = __expf(d8[l] - dmax);
    pa += wp * hv8[l]; sa += ws * hv8[l]; pw += wp; sw += ws;
  }
  subP[w][c] = pa; subS[w][c] = sa;
  if (c == 0) { subPw[w] = pw; subSw[w] = sw; }
  __syncthreads();

  if (w == 0) {
    float tp = subP[0][c] + subP[1][c] + subP[2][c] + subP[3][c];
    float ts = subS[0][c] + subS[1][c] + subS[2][c] + subS[3][c];
    chunkP[(g * NCH + ch) * 64 + c] = tp;
    chunkS[(g * NCH + ch) * 64 + c] = ts;
    if (c == 0) {
      chunkPw[g * NCH + ch] = subPw[0] + subPw[1] + subPw[2] + subPw[3];
      chunkSw[g * NCH + ch] = subSw[0] + subSw[1] + subSw[2] + subSw[3];
    }
  }
}

// ---------------- Kernel 3b: offsets + final scan write (4 waves/block, batched loads) ----------------
__global__ __launch_bounds__(256) void k_fin(const float* __restrict__ Hmat,
                                             const float* __restrict__ dsort,
                                             const int* __restrict__ perm,
                                             const float* __restrict__ chunkP, const float* __restrict__ chunkS,
                                             const float* __restrict__ chunkPw, const float* __restrict__ chunkSw,
                                             float* __restrict__ Ph, float* __restrict__ Sh,
                                             float* __restrict__ Pexp, float* __restrict__ Sexp) {
  __shared__ float subP[4][64], subS[4][64];
  __shared__ float subPw[4], subSw[4];
  __shared__ float ppart[4][64], spart[4][64];
  const int ch = blockIdx.x;   // 0..127
  const int g = blockIdx.y;    // 0..7
  const int b = g >> 2, h = g & 3;
  const int c = threadIdx.x & 63;
  const int w = threadIdx.x >> 6;
  const int gNN = g * NN;
  const size_t bNN = (size_t)b * NN;
  const int h64 = h * 64;
  const float dmax = dsort[gNN + NN - 1];
  const int kw0 = ch * CH + w * SUB;

  // --- phase 1: batched loads + local sub-chunk sums ---
  int j8[SUB]; float d8[SUB], hv8[SUB], wp8[SUB], ws8[SUB];
  #pragma unroll
  for (int l = 0; l < SUB; ++l) j8[l] = perm[gNN + kw0 + l];
  #pragma unroll
  for (int l = 0; l < SUB; ++l) d8[l] = dsort[gNN + kw0 + l];
  #pragma unroll
  for (int l = 0; l < SUB; ++l) hv8[l] = Hmat[(bNN + j8[l]) * NF + h64 + c];

  float pa = 0.f, sa = 0.f, pwl = 0.f, swl = 0.f;
  #pragma unroll
  for (int l = 0; l < SUB; ++l) {
    wp8[l] = __expf(0.2f * (d8[l] - dmax));
    ws8[l] = __expf(d8[l] - dmax);
    pa += wp8[l] * hv8[l]; sa += ws8[l] * hv8[l];
    pwl += wp8[l]; swl += ws8[l];
  }
  subP[w][c] = pa; subS[w][c] = sa;
  if (c == 0) { subPw[w] = pwl; subSw[w] = swl; }

  // --- phase 2: cross-chunk channel offsets, split across the 4 waves ---
  float pp = 0.f, sp = 0.f;
  for (int t = w; t < ch; t += 4)            pp += chunkP[(g * NCH + t) * 64 + c];
  for (int t = ch + 1 + w; t < NCH; t += 4)  sp += chunkS[(g * NCH + t) * 64 + c];
  ppart[w][c] = pp; spart[w][c] = sp;

  // scalar weight offsets: lane-parallel + wave reduce (cheap, each wave redundant)
  float w1 = chunkPw[g * NCH + c];
  float w2 = chunkPw[g * NCH + 64 + c];
  float pwo = (c < ch ? w1 : 0.f) + (c + 64 < ch ? w2 : 0.f);
  float u1 = chunkSw[g * NCH + c];
  float u2 = chunkSw[g * NCH + 64 + c];
  float swo = (c > ch ? u1 : 0.f) + (c + 64 > ch ? u2 : 0.f);
  #pragma unroll
  for (int off = 1; off < 64; off <<= 1) {
    pwo += __shfl_xor(pwo, off);
    swo += __shfl_xor(swo, off);
  }

  __syncthreads();

  // --- phase 3: assemble this wave's starting offsets ---
  float poffv = ppart[0][c] + ppart[1][c] + ppart[2][c] + ppart[3][c];
  float soffv = spart[0][c] + spart[1][c] + spart[2][c] + spart[3][c];
  float intraP = 0.f, intraS = 0.f, intraPw = 0.f, intraSw = 0.f;
  #pragma unroll
  for (int t = 0; t < 4; ++t) {
    if (t < w) { intraP += subP[t][c]; intraPw += subPw[t]; }
    if (t > w) { intraS += subS[t][c]; intraSw += subSw[t]; }
  }

  // --- phase 4: replay registers, write running prefix/suffix ---
  float rp = poffv + intraP, rw = pwo + intraPw;
  #pragma unroll
  for (int l = 0; l < SUB; ++l) {
    int k = kw0 + l;
    rp += wp8[l] * hv8[l]; rw += wp8[l];
    Ph[((size_t)(gNN + k)) * 64 + c] = rp;
    if (c == 0) Pexp[gNN + k] = rw;
  }
  float rs = soffv + intraS, rsw = swo + intraSw;
  #pragma unroll
  for (int l = SUB - 1; l >= 0; --l) {
    int k = kw0 + l;
    rs += ws8[l] * hv8[l]; rsw += ws8[l];
    Sh[((size_t)(gNN + k)) * 64 + c] = rs;
    if (c == 0) Sexp[gNN + k] = rsw;
  }
}

// ---------------- Kernel 4: per-row combine + bias + ELU ----------------
__global__ __launch_bounds__(256) void k_out(const float* __restrict__ s_arr,
                                             const float* __restrict__ dsort,
                                             const float* __restrict__ Ph, const float* __restrict__ Sh,
                                             const float* __restrict__ Pexp, const float* __restrict__ Sexp,
                                             const float* __restrict__ bias,
                                             float* __restrict__ out) {
  const int lane = threadIdx.x & 63;
  const int task = blockIdx.x * 4 + (threadIdx.x >> 6);  // 0..32767
  const int g = task >> 12;                              // 0..7
  const int i = task & (NN - 1);
  const int b = g >> 2, h = g & 3;

  const float si = s_arr[g * NN + i];
  const float t = -si;
  const float* ds = dsort + (size_t)g * NN;
  const float dmax = ds[NN - 1];

  // 64-ary search: rank m = #{ d_j <= t }
  float probe1 = ds[lane * 64 + 63];
  unsigned long long m1 = __ballot(probe1 <= t);
  int blk = __popcll(m1);
  int m;
  if (blk == 64) {
    m = NN;
  } else {
    float probe2 = ds[blk * 64 + lane];
    unsigned long long m2 = __ballot(probe2 <= t);
    m = blk * 64 + __popcll(m2);
  }

  const float sdm = si + dmax;
  const float mx = sdm > 0.f ? sdm : 0.2f * sdm;   // true row max of LeakyReLU scores
  const float alpha = __expf(sdm - mx);
  const float beta = __expf(0.2f * sdm - mx);

  float numA = 0.f, denA = 0.f, numB = 0.f, denB = 0.f;
  if (m < NN) {
    numA = Sh[((size_t)g * NN + m) * 64 + lane];
    denA = Sexp[g * NN + m];
  }
  if (m > 0) {
    numB = Ph[((size_t)g * NN + m - 1) * 64 + lane];
    denB = Pexp[g * NN + m - 1];
  }
  const float den = alpha * denA + beta * denB;
  float val = (alpha * numA + beta * numB) / den + bias[h * 64 + lane];
  float o = val > 0.f ? val : expm1f(val);
  out[((size_t)(b * NN + i)) * NF + h * 64 + lane] = o;
}

extern "C" void kernel_launch(void* const* d_in, const int* in_sizes, int n_in,
                              void* d_out, int out_size, void* d_ws, size_t ws_size,
                              hipStream_t stream) {
  const float* X = (const float*)d_in[0];       // [2,4096,128]
  const float* W = (const float*)d_in[1];       // [128,256]
  const float* a_src = (const float*)d_in[2];   // [4,64,1]
  const float* a_dst = (const float*)d_in[3];   // [4,64,1]
  const float* bias = (const float*)d_in[4];    // [256]
  float* out = (float*)d_out;                   // [2,4096,256]

  // h lives in d_out until k_out overwrites it (k_out doesn't read h)
  float* Hmat = (float*)d_out;

  float* ws = (float*)d_ws;
  float* s_arr = ws;                    // 8*4096
  float* d_arr = s_arr + NG * NN;       // 8*4096
  float* dsort = d_arr + NG * NN;       // 8*4096
  int* perm = (int*)(dsort + NG * NN);  // 8*4096
  float* Pexp = (float*)(perm + NG * NN);
  float* Sexp = Pexp + NG * NN;
  float* chunkP = Sexp + NG * NN;       // 8*128*64
  float* chunkS = chunkP + NG * NCH * 64;
  float* chunkPw = chunkS + NG * NCH * 64;  // 8*128
  float* chunkSw = chunkPw + NG * NCH;
  float* Ph = chunkSw + NG * NCH;       // 8*4096*64
  float* Sh = Ph + (size_t)NG * NN * 64;

  k_gemm<<<dim3(128, 4), 256, 0, stream>>>(X, W, a_src, a_dst, Hmat, s_arr, d_arr);
  k_sort<<<NG, 1024, 0, stream>>>(d_arr, dsort, perm);
  k_part<<<dim3(NCH, NG), 256, 0, stream>>>(Hmat, dsort, perm, chunkP, chunkS, chunkPw, chunkSw);
  k_fin<<<dim3(NCH, NG), 256, 0, stream>>>(Hmat, dsort, perm, chunkP, chunkS, chunkPw, chunkSw,
                                           Ph, Sh, Pexp, Sexp);
  k_out<<<32768 / 4, 256, 0, stream>>>(s_arr, dsort, Ph, Sh, Pexp, Sexp, bias, out);
}

// Round 4
// 69.524 us; speedup vs baseline: 6.2461x; 1.1859x over previous
//
#include <hip/hip_runtime.h>
#include <hip/hip_fp16.h>
#include <math.h>

#define NH 4        // heads
#define DD 64       // out features per head
#define NF 256      // NH*DD
#define KF 128      // in features
#define NN 4096     // nodes
#define NB 2        // batch
#define NG 8        // NB*NH groups
#define CH 32       // scan chunk length
#define NCH 128     // NN / CH
#define SUB 8       // elements per wave within a chunk (4 waves * 8 = CH)

// ---------------- Kernel 1: H = X @ W  (fp32 math, fp16 H store), fused s/d epilogue ----------------
__global__ __launch_bounds__(256) void k_gemm(const float* __restrict__ X,
                                              const float* __restrict__ W,
                                              const float* __restrict__ a_src,
                                              const float* __restrict__ a_dst,
                                              __half* __restrict__ Hout,
                                              float* __restrict__ s_arr,
                                              float* __restrict__ d_arr) {
  __shared__ float As[64][132];
  const int bm = blockIdx.x;               // 0..127
  const int bn = blockIdx.y;               // 0..3 (head)
  const int tid = threadIdx.x;

  for (int i = tid; i < 64 * 32; i += 256) {
    int r = i >> 5, c4 = i & 31;
    float4 v = *(const float4*)(X + ((size_t)(bm * 64 + r)) * KF + c4 * 4);
    *(float4*)&As[r][c4 * 4] = v;
  }
  __syncthreads();

  const int ty = tid >> 4, tx = tid & 15;
  const int col0 = bn * 64 + tx * 4;
  const float* Wp = W + col0;              // stride NF
  float acc[4][4] = {{0.f}};

  #pragma unroll 2
  for (int k4 = 0; k4 < 32; ++k4) {
    float4 a[4];
    #pragma unroll
    for (int i = 0; i < 4; ++i) a[i] = *(const float4*)&As[ty * 4 + i][k4 * 4];
    #pragma unroll
    for (int jk = 0; jk < 4; ++jk) {
      float4 b = *(const float4*)(Wp + (size_t)(k4 * 4 + jk) * NF);
      #pragma unroll
      for (int i = 0; i < 4; ++i) {
        float av = ((const float*)&a[i])[jk];
        acc[i][0] += av * b.x;
        acc[i][1] += av * b.y;
        acc[i][2] += av * b.z;
        acc[i][3] += av * b.w;
      }
    }
  }

  const float4 asv = *(const float4*)(a_src + bn * 64 + tx * 4);
  const float4 adv = *(const float4*)(a_dst + bn * 64 + tx * 4);
  const int grow0 = bm * 64 + ty * 4;
  #pragma unroll
  for (int i = 0; i < 4; ++i) {
    int grow = grow0 + i;
    union { __half2 h2[2]; float2 f2; } u;
    u.h2[0] = __floats2half2_rn(acc[i][0], acc[i][1]);
    u.h2[1] = __floats2half2_rn(acc[i][2], acc[i][3]);
    *(float2*)&Hout[(size_t)grow * NF + col0] = u.f2;
    float ps = acc[i][0] * asv.x + acc[i][1] * asv.y + acc[i][2] * asv.z + acc[i][3] * asv.w;
    float pd = acc[i][0] * adv.x + acc[i][1] * adv.y + acc[i][2] * adv.z + acc[i][3] * adv.w;
    #pragma unroll
    for (int off = 1; off < 16; off <<= 1) {
      ps += __shfl_xor(ps, off);
      pd += __shfl_xor(pd, off);
    }
    if (tx == 0) {
      int b = grow >> 12, n = grow & (NN - 1);
      int g = b * NH + bn;
      s_arr[g * NN + n] = ps;
      d_arr[g * NN + n] = pd;
    }
  }
}

// ---------------- Kernel 2: per-(b,h) bitonic sort, 4-consecutive ownership ----------------
// thread owns elements 4t..4t+3: j=1,2 register-local; j=4..128 shuffles; j=256..2048 LDS (10 passes)
__global__ __launch_bounds__(1024) void k_sort(const float* __restrict__ d_arr,
                                               float* __restrict__ dsort,
                                               int* __restrict__ perm) {
  __shared__ float4 skey[1024];
  __shared__ int4 sidx[1024];
  const int g = blockIdx.x;
  const int tid = threadIdx.x;

  float kk[4];
  int ii[4];
  {
    float4 kv = *(const float4*)(d_arr + g * NN + 4 * tid);
    kk[0] = kv.x; kk[1] = kv.y; kk[2] = kv.z; kk[3] = kv.w;
    ii[0] = 4 * tid; ii[1] = 4 * tid + 1; ii[2] = 4 * tid + 2; ii[3] = 4 * tid + 3;
  }

  // in-thread compare-exchange (a = lower index)
  #define CE(a, b, asc)                                            \
    do { if ((kk[a] > kk[b]) == (asc)) {                           \
      float tk = kk[a]; kk[a] = kk[b]; kk[b] = tk;                 \
      int ti = ii[a]; ii[a] = ii[b]; ii[b] = ti; } } while (0)

  // k = 2: pairs (0,1) asc, (2,3) desc
  CE(0, 1, true);
  CE(2, 3, false);

  #pragma unroll
  for (int k = 4; k <= NN; k <<= 1) {
    const bool asc = (tid & (k >> 2)) == 0;
    #pragma unroll
    for (int j = k >> 1; j > 0; j >>= 1) {
      if (j >= 256) {
        const int tdist = j >> 2;
        skey[tid] = make_float4(kk[0], kk[1], kk[2], kk[3]);
        sidx[tid] = make_int4(ii[0], ii[1], ii[2], ii[3]);
        __syncthreads();
        float4 pk4 = skey[tid ^ tdist];
        int4 pi4 = sidx[tid ^ tdist];
        const bool lower = (tid & tdist) == 0;
        #pragma unroll
        for (int r = 0; r < 4; ++r) {
          float pk = (&pk4.x)[r];
          int pid = (&pi4.x)[r];
          float kl = lower ? kk[r] : pk;
          float kh = lower ? pk : kk[r];
          if ((kl > kh) == asc) { kk[r] = pk; ii[r] = pid; }
        }
        __syncthreads();
      } else if (j >= 4) {
        const int dist = j >> 2;
        const bool lower = (tid & dist) == 0;
        #pragma unroll
        for (int r = 0; r < 4; ++r) {
          float pk = __shfl_xor(kk[r], dist);
          int pid = __shfl_xor(ii[r], dist);
          float kl = lower ? kk[r] : pk;
          float kh = lower ? pk : kk[r];
          if ((kl > kh) == asc) { kk[r] = pk; ii[r] = pid; }
        }
      } else if (j == 2) {
        CE(0, 2, asc);
        CE(1, 3, asc);
      } else {
        CE(0, 1, asc);
        CE(2, 3, asc);
      }
    }
  }
  #undef CE

  *(float4*)(dsort + g * NN + 4 * tid) = make_float4(kk[0], kk[1], kk[2], kk[3]);
  *(int4*)(perm + g * NN + 4 * tid) = make_int4(ii[0], ii[1], ii[2], ii[3]);
}

// ---------------- Kernel 3a: per-chunk partial sums (4 waves/block, batched loads) ----------------
__global__ __launch_bounds__(256) void k_part(const __half* __restrict__ Hmat,
                                              const float* __restrict__ dsort,
                                              const int* __restrict__ perm,
                                              float* __restrict__ chunkP, float* __restrict__ chunkS,
                                              float* __restrict__ chunkPw, float* __restrict__ chunkSw) {
  __shared__ float subP[4][64], subS[4][64];
  __shared__ float subPw[4], subSw[4];
  const int ch = blockIdx.x;   // 0..127
  const int g = blockIdx.y;    // 0..7
  const int b = g >> 2, h = g & 3;
  const int c = threadIdx.x & 63;
  const int w = threadIdx.x >> 6;
  const int gNN = g * NN;
  const size_t bNN = (size_t)b * NN;
  const int h64 = h * 64;
  const float dmax = dsort[gNN + NN - 1];
  const int kw0 = ch * CH + w * SUB;

  int j8[SUB]; float d8[SUB], hv8[SUB];
  #pragma unroll
  for (int l = 0; l < SUB; ++l) j8[l] = perm[gNN + kw0 + l];
  #pragma unroll
  for (int l = 0; l < SUB; ++l) d8[l] = dsort[gNN + kw0 + l];
  #pragma unroll
  for (int l = 0; l < SUB; ++l) hv8[l] = __half2float(Hmat[(bNN + j8[l]) * NF + h64 + c]);

  float pa = 0.f, sa = 0.f, pw = 0.f, sw = 0.f;
  #pragma unroll
  for (int l = 0; l < SUB; ++l) {
    float wp = __expf(0.2f * (d8[l] - dmax));
    float ws = __expf(d8[l] - dmax);
    pa += wp * hv8[l]; sa += ws * hv8[l]; pw += wp; sw += ws;
  }
  subP[w][c] = pa; subS[w][c] = sa;
  if (c == 0) { subPw[w] = pw; subSw[w] = sw; }
  __syncthreads();

  if (w == 0) {
    float tp = subP[0][c] + subP[1][c] + subP[2][c] + subP[3][c];
    float ts = subS[0][c] + subS[1][c] + subS[2][c] + subS[3][c];
    chunkP[(g * NCH + ch) * 64 + c] = tp;
    chunkS[(g * NCH + ch) * 64 + c] = ts;
    if (c == 0) {
      chunkPw[g * NCH + ch] = subPw[0] + subPw[1] + subPw[2] + subPw[3];
      chunkSw[g * NCH + ch] = subSw[0] + subSw[1] + subSw[2] + subSw[3];
    }
  }
}

// ---------------- Kernel 3b: offsets + final scan write (fp16 Ph/Sh) ----------------
__global__ __launch_bounds__(256) void k_fin(const __half* __restrict__ Hmat,
                                             const float* __restrict__ dsort,
                                             const int* __restrict__ perm,
                                             const float* __restrict__ chunkP, const float* __restrict__ chunkS,
                                             const float* __restrict__ chunkPw, const float* __restrict__ chunkSw,
                                             __half* __restrict__ Ph, __half* __restrict__ Sh,
                                             float* __restrict__ Pexp, float* __restrict__ Sexp) {
  __shared__ float subP[4][64], subS[4][64];
  __shared__ float subPw[4], subSw[4];
  __shared__ float ppart[4][64], spart[4][64];
  const int ch = blockIdx.x;   // 0..127
  const int g = blockIdx.y;    // 0..7
  const int b = g >> 2, h = g & 3;
  const int c = threadIdx.x & 63;
  const int w = threadIdx.x >> 6;
  const int gNN = g * NN;
  const size_t bNN = (size_t)b * NN;
  const int h64 = h * 64;
  const float dmax = dsort[gNN + NN - 1];
  const int kw0 = ch * CH + w * SUB;

  // --- phase 1: batched loads + local sub-chunk sums ---
  int j8[SUB]; float d8[SUB], hv8[SUB], wp8[SUB], ws8[SUB];
  #pragma unroll
  for (int l = 0; l < SUB; ++l) j8[l] = perm[gNN + kw0 + l];
  #pragma unroll
  for (int l = 0; l < SUB; ++l) d8[l] = dsort[gNN + kw0 + l];
  #pragma unroll
  for (int l = 0; l < SUB; ++l) hv8[l] = __half2float(Hmat[(bNN + j8[l]) * NF + h64 + c]);

  float pa = 0.f, sa = 0.f, pwl = 0.f, swl = 0.f;
  #pragma unroll
  for (int l = 0; l < SUB; ++l) {
    wp8[l] = __expf(0.2f * (d8[l] - dmax));
    ws8[l] = __expf(d8[l] - dmax);
    pa += wp8[l] * hv8[l]; sa += ws8[l] * hv8[l];
    pwl += wp8[l]; swl += ws8[l];
  }
  subP[w][c] = pa; subS[w][c] = sa;
  if (c == 0) { subPw[w] = pwl; subSw[w] = swl; }

  // --- phase 2: cross-chunk channel offsets, split across the 4 waves ---
  float pp = 0.f, sp = 0.f;
  for (int t = w; t < ch; t += 4)            pp += chunkP[(g * NCH + t) * 64 + c];
  for (int t = ch + 1 + w; t < NCH; t += 4)  sp += chunkS[(g * NCH + t) * 64 + c];
  ppart[w][c] = pp; spart[w][c] = sp;

  // scalar weight offsets: lane-parallel + wave reduce (each wave redundant, cheap)
  float w1 = chunkPw[g * NCH + c];
  float w2 = chunkPw[g * NCH + 64 + c];
  float pwo = (c < ch ? w1 : 0.f) + (c + 64 < ch ? w2 : 0.f);
  float u1 = chunkSw[g * NCH + c];
  float u2 = chunkSw[g * NCH + 64 + c];
  float swo = (c > ch ? u1 : 0.f) + (c + 64 > ch ? u2 : 0.f);
  #pragma unroll
  for (int off = 1; off < 64; off <<= 1) {
    pwo += __shfl_xor(pwo, off);
    swo += __shfl_xor(swo, off);
  }

  __syncthreads();

  // --- phase 3: assemble this wave's starting offsets ---
  float poffv = ppart[0][c] + ppart[1][c] + ppart[2][c] + ppart[3][c];
  float soffv = spart[0][c] + spart[1][c] + spart[2][c] + spart[3][c];
  float intraP = 0.f, intraS = 0.f, intraPw = 0.f, intraSw = 0.f;
  #pragma unroll
  for (int t = 0; t < 4; ++t) {
    if (t < w) { intraP += subP[t][c]; intraPw += subPw[t]; }
    if (t > w) { intraS += subS[t][c]; intraSw += subSw[t]; }
  }

  // --- phase 4: replay registers, write running prefix/suffix (fp32 accum, fp16 store) ---
  float rp = poffv + intraP, rw = pwo + intraPw;
  #pragma unroll
  for (int l = 0; l < SUB; ++l) {
    int k = kw0 + l;
    rp += wp8[l] * hv8[l]; rw += wp8[l];
    Ph[((size_t)(gNN + k)) * 64 + c] = __float2half(rp);
    if (c == 0) Pexp[gNN + k] = rw;
  }
  float rs = soffv + intraS, rsw = swo + intraSw;
  #pragma unroll
  for (int l = SUB - 1; l >= 0; --l) {
    int k = kw0 + l;
    rs += ws8[l] * hv8[l]; rsw += ws8[l];
    Sh[((size_t)(gNN + k)) * 64 + c] = __float2half(rs);
    if (c == 0) Sexp[gNN + k] = rsw;
  }
}

// ---------------- Kernel 4: per-row combine + bias + ELU ----------------
__global__ __launch_bounds__(256) void k_out(const float* __restrict__ s_arr,
                                             const float* __restrict__ dsort,
                                             const __half* __restrict__ Ph, const __half* __restrict__ Sh,
                                             const float* __restrict__ Pexp, const float* __restrict__ Sexp,
                                             const float* __restrict__ bias,
                                             float* __restrict__ out) {
  const int lane = threadIdx.x & 63;
  const int task = blockIdx.x * 4 + (threadIdx.x >> 6);  // 0..32767
  const int g = task >> 12;                              // 0..7
  const int i = task & (NN - 1);
  const int b = g >> 2, h = g & 3;

  const float si = s_arr[g * NN + i];
  const float t = -si;
  const float* ds = dsort + (size_t)g * NN;
  const float dmax = ds[NN - 1];

  // 64-ary search: rank m = #{ d_j <= t }
  float probe1 = ds[lane * 64 + 63];
  unsigned long long m1 = __ballot(probe1 <= t);
  int blk = __popcll(m1);
  int m;
  if (blk == 64) {
    m = NN;
  } else {
    float probe2 = ds[blk * 64 + lane];
    unsigned long long m2 = __ballot(probe2 <= t);
    m = blk * 64 + __popcll(m2);
  }

  const float sdm = si + dmax;
  const float mx = sdm > 0.f ? sdm : 0.2f * sdm;   // true row max of LeakyReLU scores
  const float alpha = __expf(sdm - mx);
  const float beta = __expf(0.2f * sdm - mx);

  float numA = 0.f, denA = 0.f, numB = 0.f, denB = 0.f;
  if (m < NN) {
    numA = __half2float(Sh[((size_t)(g * NN + m)) * 64 + lane]);
    denA = Sexp[g * NN + m];
  }
  if (m > 0) {
    numB = __half2float(Ph[((size_t)(g * NN + m - 1)) * 64 + lane]);
    denB = Pexp[g * NN + m - 1];
  }
  const float den = alpha * denA + beta * denB;
  float val = (alpha * numA + beta * numB) / den + bias[h * 64 + lane];
  float o = val > 0.f ? val : expm1f(val);
  out[((size_t)(b * NN + i)) * NF + h * 64 + lane] = o;
}

extern "C" void kernel_launch(void* const* d_in, const int* in_sizes, int n_in,
                              void* d_out, int out_size, void* d_ws, size_t ws_size,
                              hipStream_t stream) {
  const float* X = (const float*)d_in[0];       // [2,4096,128]
  const float* W = (const float*)d_in[1];       // [128,256]
  const float* a_src = (const float*)d_in[2];   // [4,64,1]
  const float* a_dst = (const float*)d_in[3];   // [4,64,1]
  const float* bias = (const float*)d_in[4];    // [256]
  float* out = (float*)d_out;                   // [2,4096,256]

  float* ws = (float*)d_ws;
  float* s_arr = ws;                    // 8*4096
  float* d_arr = s_arr + NG * NN;       // 8*4096
  float* dsort = d_arr + NG * NN;       // 8*4096
  int* perm = (int*)(dsort + NG * NN);  // 8*4096
  float* Pexp = (float*)(perm + NG * NN);
  float* Sexp = Pexp + NG * NN;
  float* chunkP = Sexp + NG * NN;       // 8*128*64
  float* chunkS = chunkP + NG * NCH * 64;
  float* chunkPw = chunkS + NG * NCH * 64;  // 8*128
  float* chunkSw = chunkPw + NG * NCH;
  __half* Hmat = (__half*)(chunkSw + NG * NCH);     // 2*4096*256 halves (4 MB)
  __half* Ph = Hmat + (size_t)NB * NN * NF;         // 8*4096*64 halves
  __half* Sh = Ph + (size_t)NG * NN * 64;

  k_gemm<<<dim3(128, 4), 256, 0, stream>>>(X, W, a_src, a_dst, Hmat, s_arr, d_arr);
  k_sort<<<NG, 1024, 0, stream>>>(d_arr, dsort, perm);
  k_part<<<dim3(NCH, NG), 256, 0, stream>>>(Hmat, dsort, perm, chunkP, chunkS, chunkPw, chunkSw);
  k_fin<<<dim3(NCH, NG), 256, 0, stream>>>(Hmat, dsort, perm, chunkP, chunkS, chunkPw, chunkSw,
                                           Ph, Sh, Pexp, Sexp);
  k_out<<<32768 / 4, 256, 0, stream>>>(s_arr, dsort, Ph, Sh, Pexp, Sexp, bias, out);
}